// Round 16
// baseline (109.521 us; speedup 1.0000x reference)
//
#include <hip/hip_runtime.h>
#include <hip/hip_bf16.h>

#define NT 512
#define TB 16   // batch elements per block

typedef unsigned short u16;
typedef unsigned int u32;
typedef __attribute__((ext_vector_type(8))) short short8v;  // 8 bf16 (4 VGPRs)
typedef __attribute__((ext_vector_type(4))) float f32x4;

__device__ __forceinline__ float bf2f(u16 u) {
  union { u32 i; float f; } v; v.i = ((u32)u) << 16; return v.f;
}
__device__ __forceinline__ float2 up2(u32 p) {
  union { u32 i; float f; } a, b;
  a.i = p << 16; b.i = p & 0xffff0000u;
  return make_float2(a.f, b.f);
}
__device__ __forceinline__ u16 f2bf(float f) {
  union { float f; u32 i; } v; v.f = f;
  u32 r = v.i + 0x7fffu + ((v.i >> 16) & 1u);  // round-to-nearest-even
  return (u16)(r >> 16);
}
// single-instruction pair pack: low16 = bf16(a), high16 = bf16(b)  [T12 recipe]
// NOTE (R15 post-mortem): only feed this values produced by ordinary VALU ops.
// Feeding MFMA accumulator registers DIRECTLY into this inline asm produced
// garbage (suspected missed MFMA->VALU hazard nops for inline-asm consumers).
__device__ __forceinline__ u32 pk2c(float a, float b) {
  u32 r;
  asm("v_cvt_pk_bf16_f32 %0, %1, %2" : "=v"(r) : "v"(a), "v"(b));
  return r;
}

// ws layout: f32 s1bp[20][64] @0 ; then u16 block at ws+1280:
//   wqkv [192][64] @0 | s2w [32][64] @12288 | ow [64][64] @14336 | g2w [32][64] @18432
//   c1w [128][96] @20480 | c2w [128][128] @32768 | s1wA [64][128] @49152
// Parallel prep (R13): blocks 0..31 convert weights; block 32 does arep+s1bp.
__global__ void prep_kernel(const float* __restrict__ emb, const int* __restrict__ act_idx,
                            const int* __restrict__ act_cnt, const float* __restrict__ s1w,
                            const float* __restrict__ s1b, const float* __restrict__ ipw,
                            const float* __restrict__ s2w, const float* __restrict__ ow,
                            const float* __restrict__ g2w, const float* __restrict__ c1w,
                            const float* __restrict__ c2w, float* __restrict__ ws) {
  __shared__ float s_arep[20][64];
  const int b = blockIdx.x, t = threadIdx.x;
  if (b < 32) {
    const int tid = b * 256 + t;             // 0..8191, stride 8192
    u16* wbf = (u16*)(ws + 1280);
    for (int o = tid; o < 12288; o += 8192) wbf[o] = f2bf(ipw[o]);
    for (int o = tid; o < 2048;  o += 8192) wbf[12288 + o] = f2bf(s2w[o]);
    for (int o = tid; o < 4096;  o += 8192) wbf[14336 + o] = f2bf(ow[o]);
    for (int o = tid; o < 2048;  o += 8192) wbf[18432 + o] = f2bf(g2w[o]);
    for (int o = tid; o < 12288; o += 8192) wbf[20480 + o] = f2bf(c1w[o]);
    for (int o = tid; o < 16384; o += 8192) wbf[32768 + o] = f2bf(c2w[o]);
    for (int o = tid; o < 8192;  o += 8192) {
      int f = o >> 7, k = o & 127;
      wbf[49152 + o] = f2bf(s1w[f * 192 + k]);
    }
  } else {
    for (int o = t; o < 20 * 64; o += 256) {
      int a = o >> 6, k = o & 63;
      int cnt = act_cnt[a];
      float sum = 0.f;
#pragma unroll
      for (int j = 0; j < 4; ++j)
        if (j < cnt) sum += emb[act_idx[a * 4 + j] * 64 + k];
      s_arep[a][k] = sum / (float)(cnt > 1 ? cnt : 1);
    }
    __syncthreads();
    for (int o = t; o < 20 * 64; o += 256) {
      int a = o >> 6, f = o & 63;
      const float* wr = s1w + f * 192 + 128;
      float acc = s1b[f];
#pragma unroll 8
      for (int k = 0; k < 64; ++k) acc += s_arep[a][k] * wr[k];
      ws[o] = acc;
    }
  }
}

// LDS map (bytes), total 52544; TB=16, NT=512 (8 waves):
//  [0..51200): x[128][72] u16 -> qkv[128][200] u16 (attention); ah overlays q-cols
//    then MLP bf16: hxbf[16][72]@0 g1bf[16][72]@2304 ctxin[16][104]@4608
//      ctxbf[16][136]@7936 ctx2bf[16][136]@12288 (end 16640)
//    then hbf[320][72] u16 @0..46080 (P9 staged; fused version regressed — R13)
//  s1a f32 [16][68] @46080..50432
//  extras: cards@51200 invlen@51712 gs@51776 (end 52544)
//  3 blocks/CU (LDS-bound), 24 waves/CU.
__global__ __launch_bounds__(NT, 6) void policy_fused(
    const int* __restrict__ hand_cards, const float* __restrict__ game_state,
    const int* __restrict__ hand_size, const int* __restrict__ num_valid,
    const float* __restrict__ emb, const float* __restrict__ ipb,
    const float* __restrict__ ob, const float* __restrict__ g1w,
    const float* __restrict__ g1b, const float* __restrict__ g2b,
    const float* __restrict__ c1b, const float* __restrict__ c2b,
    const float* __restrict__ s2b, const float* __restrict__ s3w,
    const float* __restrict__ s3b, const float* __restrict__ ws,
    float* __restrict__ out)
{
  __shared__ __align__(16) unsigned char s_raw[52544];
  u16*   s_x     = (u16*)s_raw;                 // [128][72]
  u16*   s_qkv   = (u16*)s_raw;                 // [128][200]; ah -> cols 0..63
  u16*   s_hxbf  = (u16*)(s_raw + 0);           // [16][72]
  u16*   s_g1bf  = (u16*)(s_raw + 2304);        // [16][72]
  u16*   s_ctxin = (u16*)(s_raw + 4608);        // [16][104] hand|g
  u16*   s_ctxbf = (u16*)(s_raw + 7936);        // [16][136]
  u16*   s_ctx2bf= (u16*)(s_raw + 12288);       // [16][136]
  u16*   s_hbf   = (u16*)s_raw;                 // [320][72] (P9)
  float* s_s1a   = (float*)(s_raw + 46080);     // [16][68]
  int*   s_cards  = (int*)(s_raw + 51200);      // [128]
  float* s_invlen = (float*)(s_raw + 51712);    // [16]
  float* s_gs    = (float*)(s_raw + 51776);     // [16][12]

  const float* ws_s1bp = ws;                         // [20][64]
  const u16* wbf    = (const u16*)(ws + 1280);
  const u16* wqkv   = wbf;                           // [192][64]
  const u16* s2wbf  = wbf + 12288;                   // [32][64]
  const u16* owbf   = wbf + 14336;                   // [64][64]
  const u16* g2wbf  = wbf + 18432;                   // [32][64]
  const u16* c1wbf  = wbf + 20480;                   // [128][96]
  const u16* c2wbf  = wbf + 32768;                   // [128][128]
  const u16* s1wbf  = wbf + 49152;                   // [64][128]

  const int t = threadIdx.x;
  const int base = blockIdx.x * TB;
  const int lw = t & 63, wv = t >> 6;     // 8 waves
  const int kq = lw >> 4, rr = lw & 15;   // MFMA: A row / C col = rr; k-chunk & C row-group = kq
  const int row0 = kq * 4;

  // ---- P0a ----
  if (t < 128) s_cards[t] = hand_cards[base * 8 + t];
  if (t < TB) { int hs = hand_size[base + t]; s_invlen[t] = 1.0f / (float)(hs > 1 ? hs : 1); }
  if (t >= 128 && t < 128 + TB * 12) {
    int i = t - 128; s_gs[(i / 12) * 12 + (i % 12)] = game_state[(base + i / 12) * 12 + i % 12];
  }
  __syncthreads();

  // ---- P0b: gather x = emb[cards] -> bf16 LDS ----
  {
    int es = t >> 2, k0 = (t & 3) * 16;            // 128 tokens x 4 threads
    const float* src = emb + s_cards[es] * 64 + k0;
    float4 v0 = *(const float4*)(src);
    float4 v1 = *(const float4*)(src + 4);
    float4 v2 = *(const float4*)(src + 8);
    float4 v3 = *(const float4*)(src + 12);
    uint4 pa = make_uint4(pk2c(v0.x,v0.y), pk2c(v0.z,v0.w), pk2c(v1.x,v1.y), pk2c(v1.z,v1.w));
    uint4 pb = make_uint4(pk2c(v2.x,v2.y), pk2c(v2.z,v2.w), pk2c(v3.x,v3.y), pk2c(v3.z,v3.w));
    *(uint4*)(s_x + es * 72 + k0) = pa;
    *(uint4*)(s_x + es * 72 + k0 + 8) = pb;
  }
  __syncthreads();

  // ---- P1: qkv = x @ ipw.T + ipb via MFMA (wave wv owns tokens 16wv..16wv+15) ----
  {
    const int tok = wv * 16 + rr;
    short8v a0 = *(const short8v*)(s_x + tok * 72 + kq * 8);
    short8v a1 = *(const short8v*)(s_x + tok * 72 + 32 + kq * 8);
    __syncthreads();   // A frags in regs; qkv may overwrite x
    const int trow = wv * 16 + row0;
    for (int n = 0; n < 12; ++n) {
      const int f = n * 16 + rr;
      short8v b0 = *(const short8v*)(wqkv + f * 64 + kq * 8);
      short8v b1 = *(const short8v*)(wqkv + f * 64 + 32 + kq * 8);
      float bias = ipb[f];
      f32x4 acc = { bias, bias, bias, bias };
      acc = __builtin_amdgcn_mfma_f32_16x16x32_bf16(a0, b0, acc, 0, 0, 0);
      acc = __builtin_amdgcn_mfma_f32_16x16x32_bf16(a1, b1, acc, 0, 0, 0);
#pragma unroll
      for (int r = 0; r < 4; ++r)
        s_qkv[(trow + r) * 200 + f] = f2bf(acc[r]);
    }
  }
  __syncthreads();

  // ---- P2+P4 merged: scores + softmax (in regs) + PV ; ah -> qkv q-cols ----
  {
    int e = t >> 5, h = (t >> 3) & 3, q = t & 7;   // e 0..15
    u16* qrow = s_qkv + (e * 8 + q) * 200 + h * 16;
    float qr[16];
    {
      uint4 ua = *(const uint4*)(qrow);
      uint4 ub = *(const uint4*)(qrow + 8);
      float2 f;
      f = up2(ua.x); qr[0]=f.x; qr[1]=f.y;  f = up2(ua.y); qr[2]=f.x; qr[3]=f.y;
      f = up2(ua.z); qr[4]=f.x; qr[5]=f.y;  f = up2(ua.w); qr[6]=f.x; qr[7]=f.y;
      f = up2(ub.x); qr[8]=f.x; qr[9]=f.y;  f = up2(ub.y); qr[10]=f.x; qr[11]=f.y;
      f = up2(ub.z); qr[12]=f.x; qr[13]=f.y; f = up2(ub.w); qr[14]=f.x; qr[15]=f.y;
    }
    float sc[8];
#pragma unroll
    for (int kk = 0; kk < 8; ++kk) {
      const u16* krow = s_qkv + (e * 8 + kk) * 200 + 64 + h * 16;
      uint4 ua = *(const uint4*)(krow);
      uint4 ub = *(const uint4*)(krow + 8);
      float a0 = 0.f;
      float2 f;
      f = up2(ua.x); a0 += qr[0]*f.x + qr[1]*f.y;
      f = up2(ua.y); a0 += qr[2]*f.x + qr[3]*f.y;
      f = up2(ua.z); a0 += qr[4]*f.x + qr[5]*f.y;
      f = up2(ua.w); a0 += qr[6]*f.x + qr[7]*f.y;
      f = up2(ub.x); a0 += qr[8]*f.x + qr[9]*f.y;
      f = up2(ub.y); a0 += qr[10]*f.x + qr[11]*f.y;
      f = up2(ub.z); a0 += qr[12]*f.x + qr[13]*f.y;
      f = up2(ub.w); a0 += qr[14]*f.x + qr[15]*f.y;
      sc[kk] = (s_cards[e * 8 + kk] != 0) ? a0 * 0.25f : -1e9f;
    }
    float m = sc[0];
#pragma unroll
    for (int kk = 1; kk < 8; ++kk) m = fmaxf(m, sc[kk]);
    float ssum = 0.f;
#pragma unroll
    for (int kk = 0; kk < 8; ++kk) { sc[kk] = __expf(sc[kk] - m); ssum += sc[kk]; }
    float inv = 1.f / ssum;
#pragma unroll
    for (int kk = 0; kk < 8; ++kk) sc[kk] *= inv;
    float acc[16];
#pragma unroll
    for (int d = 0; d < 16; ++d) acc[d] = 0.f;
#pragma unroll
    for (int kk = 0; kk < 8; ++kk) {
      const u16* vrow = s_qkv + (e * 8 + kk) * 200 + 128 + h * 16;
      uint4 ua = *(const uint4*)(vrow);
      uint4 ub = *(const uint4*)(vrow + 8);
      float2 f;
      f = up2(ua.x); acc[0] += sc[kk]*f.x; acc[1] += sc[kk]*f.y;
      f = up2(ua.y); acc[2] += sc[kk]*f.x; acc[3] += sc[kk]*f.y;
      f = up2(ua.z); acc[4] += sc[kk]*f.x; acc[5] += sc[kk]*f.y;
      f = up2(ua.w); acc[6] += sc[kk]*f.x; acc[7] += sc[kk]*f.y;
      f = up2(ub.x); acc[8] += sc[kk]*f.x; acc[9] += sc[kk]*f.y;
      f = up2(ub.y); acc[10] += sc[kk]*f.x; acc[11] += sc[kk]*f.y;
      f = up2(ub.z); acc[12] += sc[kk]*f.x; acc[13] += sc[kk]*f.y;
      f = up2(ub.w); acc[14] += sc[kk]*f.x; acc[15] += sc[kk]*f.y;
    }
    uint4 oa = make_uint4(pk2c(acc[0],acc[1]), pk2c(acc[2],acc[3]), pk2c(acc[4],acc[5]), pk2c(acc[6],acc[7]));
    uint4 oc = make_uint4(pk2c(acc[8],acc[9]), pk2c(acc[10],acc[11]), pk2c(acc[12],acc[13]), pk2c(acc[14],acc[15]));
    *(uint4*)(qrow) = oa;
    *(uint4*)(qrow + 8) = oc;
  }
  __syncthreads();

  // ---- P5a: stage hx (sum_q ah) + g1 into regs; barrier; write over dead region ----
  {
    int e = t >> 5, k2 = (t & 31) * 2;             // hx: (e 0..15, col pair)
    float s0 = 0.f, s1 = 0.f;
#pragma unroll
    for (int q = 0; q < 8; ++q) {
      float2 f = up2(*(const u32*)(s_qkv + (e * 8 + q) * 200 + k2));
      s0 += f.x; s1 += f.y;
    }
    int e1 = t >> 6, f1 = t & 63;                  // g1: e1 0..7
    float ga = g1b[f1];
#pragma unroll
    for (int k = 0; k < 12; ++k) ga += s_gs[e1 * 12 + k] * g1w[f1 * 12 + k];
    int e2 = e1 + 8;
    float gb = g1b[f1];
#pragma unroll
    for (int k = 0; k < 12; ++k) gb += s_gs[e2 * 12 + k] * g1w[f1 * 12 + k];
    __syncthreads();   // all ah reads done; attention region now dead
    *(u32*)(s_hxbf + e * 72 + k2) = pk2c(s0, s1);
    s_g1bf[e1 * 72 + f1] = f2bf(fmaxf(ga, 0.f));
    s_g1bf[e2 * 72 + f1] = f2bf(fmaxf(gb, 0.f));
  }
  __syncthreads();

  // ---- P5b: hand (waves 0..3) -> ctxin[:, :64] ; g2 (waves 4..5) -> ctxin[:, 64:96] ----
  {
    if (wv < 4) {
      short8v a0 = *(const short8v*)(s_hxbf + rr * 72 + kq * 8);
      short8v a1 = *(const short8v*)(s_hxbf + rr * 72 + 32 + kq * 8);
      const int f = wv * 16 + rr;
      short8v b0 = *(const short8v*)(owbf + f * 64 + kq * 8);
      short8v b1 = *(const short8v*)(owbf + f * 64 + 32 + kq * 8);
      float bias = 8.f * ob[f];
      f32x4 acc = { bias, bias, bias, bias };
      acc = __builtin_amdgcn_mfma_f32_16x16x32_bf16(a0, b0, acc, 0, 0, 0);
      acc = __builtin_amdgcn_mfma_f32_16x16x32_bf16(a1, b1, acc, 0, 0, 0);
#pragma unroll
      for (int r = 0; r < 4; ++r) {
        int row = row0 + r;
        s_ctxin[row * 104 + f] = f2bf(acc[r] * s_invlen[row]);
      }
    } else if (wv < 6) {
      short8v g0 = *(const short8v*)(s_g1bf + rr * 72 + kq * 8);
      short8v g1v = *(const short8v*)(s_g1bf + rr * 72 + 32 + kq * 8);
      const int f2 = (wv - 4) * 16 + rr;
      short8v c0 = *(const short8v*)(g2wbf + f2 * 64 + kq * 8);
      short8v c1 = *(const short8v*)(g2wbf + f2 * 64 + 32 + kq * 8);
      float b2 = g2b[f2];
      f32x4 acc2 = { b2, b2, b2, b2 };
      acc2 = __builtin_amdgcn_mfma_f32_16x16x32_bf16(g0, c0, acc2, 0, 0, 0);
      acc2 = __builtin_amdgcn_mfma_f32_16x16x32_bf16(g1v, c1, acc2, 0, 0, 0);
#pragma unroll
      for (int r = 0; r < 4; ++r) {
        int row = row0 + r;
        s_ctxin[row * 104 + 64 + f2] = f2bf(fmaxf(acc2[r], 0.f));
      }
    }
  }
  __syncthreads();

  // ---- P6: ctx = relu(ctxin @ c1.T + c1b), K=96 N=128 (8 waves x 16 outputs) ----
  {
    short8v a0 = *(const short8v*)(s_ctxin + rr * 104 + kq * 8);
    short8v a1 = *(const short8v*)(s_ctxin + rr * 104 + 32 + kq * 8);
    short8v a2 = *(const short8v*)(s_ctxin + rr * 104 + 64 + kq * 8);
    const int f = wv * 16 + rr;
    short8v b0 = *(const short8v*)(c1wbf + f * 96 + kq * 8);
    short8v b1 = *(const short8v*)(c1wbf + f * 96 + 32 + kq * 8);
    short8v b2 = *(const short8v*)(c1wbf + f * 96 + 64 + kq * 8);
    float bias = c1b[f];
    f32x4 acc = { bias, bias, bias, bias };
    acc = __builtin_amdgcn_mfma_f32_16x16x32_bf16(a0, b0, acc, 0, 0, 0);
    acc = __builtin_amdgcn_mfma_f32_16x16x32_bf16(a1, b1, acc, 0, 0, 0);
    acc = __builtin_amdgcn_mfma_f32_16x16x32_bf16(a2, b2, acc, 0, 0, 0);
#pragma unroll
    for (int r = 0; r < 4; ++r) {
      int row = row0 + r;
      s_ctxbf[row * 136 + f] = f2bf(fmaxf(acc[r], 0.f));
    }
  }
  __syncthreads();

  // ---- P7: ctx2 = relu(ctx @ c2.T + c2b), K=128 N=128 ----
  {
    short8v a0 = *(const short8v*)(s_ctxbf + rr * 136 + kq * 8);
    short8v a1 = *(const short8v*)(s_ctxbf + rr * 136 + 32 + kq * 8);
    short8v a2 = *(const short8v*)(s_ctxbf + rr * 136 + 64 + kq * 8);
    short8v a3 = *(const short8v*)(s_ctxbf + rr * 136 + 96 + kq * 8);
    const int f = wv * 16 + rr;
    short8v b0 = *(const short8v*)(c2wbf + f * 128 + kq * 8);
    short8v b1 = *(const short8v*)(c2wbf + f * 128 + 32 + kq * 8);
    short8v b2 = *(const short8v*)(c2wbf + f * 128 + 64 + kq * 8);
    short8v b3 = *(const short8v*)(c2wbf + f * 128 + 96 + kq * 8);
    float bias = c2b[f];
    f32x4 acc = { bias, bias, bias, bias };
    acc = __builtin_amdgcn_mfma_f32_16x16x32_bf16(a0, b0, acc, 0, 0, 0);
    acc = __builtin_amdgcn_mfma_f32_16x16x32_bf16(a1, b1, acc, 0, 0, 0);
    acc = __builtin_amdgcn_mfma_f32_16x16x32_bf16(a2, b2, acc, 0, 0, 0);
    acc = __builtin_amdgcn_mfma_f32_16x16x32_bf16(a3, b3, acc, 0, 0, 0);
#pragma unroll
    for (int r = 0; r < 4; ++r) {
      int row = row0 + r;
      s_ctx2bf[row * 136 + f] = f2bf(fmaxf(acc[r], 0.f));
    }
  }
  __syncthreads();

  // ---- P8: s1a = ctx2 @ s1w[:,:128].T (f32 out), K=128 N=64 (waves 0..3) ----
  if (wv < 4) {
    short8v a0 = *(const short8v*)(s_ctx2bf + rr * 136 + kq * 8);
    short8v a1 = *(const short8v*)(s_ctx2bf + rr * 136 + 32 + kq * 8);
    short8v a2 = *(const short8v*)(s_ctx2bf + rr * 136 + 64 + kq * 8);
    short8v a3 = *(const short8v*)(s_ctx2bf + rr * 136 + 96 + kq * 8);
    const int f = wv * 16 + rr;
    short8v b0 = *(const short8v*)(s1wbf + f * 128 + kq * 8);
    short8v b1 = *(const short8v*)(s1wbf + f * 128 + 32 + kq * 8);
    short8v b2 = *(const short8v*)(s1wbf + f * 128 + 64 + kq * 8);
    short8v b3 = *(const short8v*)(s1wbf + f * 128 + 96 + kq * 8);
    f32x4 acc = { 0.f, 0.f, 0.f, 0.f };
    acc = __builtin_amdgcn_mfma_f32_16x16x32_bf16(a0, b0, acc, 0, 0, 0);
    acc = __builtin_amdgcn_mfma_f32_16x16x32_bf16(a1, b1, acc, 0, 0, 0);
    acc = __builtin_amdgcn_mfma_f32_16x16x32_bf16(a2, b2, acc, 0, 0, 0);
    acc = __builtin_amdgcn_mfma_f32_16x16x32_bf16(a3, b3, acc, 0, 0, 0);
#pragma unroll
    for (int r = 0; r < 4; ++r)
      s_s1a[(row0 + r) * 68 + f] = acc[r];
  }
  __syncthreads();

  // ---- P9a: h[i=e*20+a][j] = relu(s1a[e][j] + s1bp[a][j]) -> bf16 [320][72] ----
  for (int o = t; o < 320 * 32; o += NT) {
    int i = o >> 5, j = (o & 31) * 2;
    int e = i / 20, a = i - e * 20;
    float2 sv = *(const float2*)(s_s1a + e * 68 + j);
    float2 bv = *(const float2*)(ws_s1bp + a * 64 + j);
    float v0 = fmaxf(sv.x + bv.x, 0.f), v1 = fmaxf(sv.y + bv.y, 0.f);
    *(u32*)(s_hbf + i * 72 + j) = pk2c(v0, v1);
  }
  __syncthreads();

  // ---- P9b: score = relu(h @ s2w.T + s2b) . s3w + s3b via MFMA (20 M-tiles / 8 waves) ----
  {
    const int nv = num_valid[0];
    const float s3b0 = s3b[0];
    for (int mt = wv; mt < 20; mt += 8) {
      const int row = mt * 16 + rr;
      short8v a0 = *(const short8v*)(s_hbf + row * 72 + kq * 8);
      short8v a1 = *(const short8v*)(s_hbf + row * 72 + 32 + kq * 8);
      float part[4] = {0.f, 0.f, 0.f, 0.f};
#pragma unroll
      for (int ntile = 0; ntile < 2; ++ntile) {
        const int m = ntile * 16 + rr;
        short8v b0 = *(const short8v*)(s2wbf + m * 64 + kq * 8);
        short8v b1 = *(const short8v*)(s2wbf + m * 64 + 32 + kq * 8);
        float bias = s2b[m];
        f32x4 acc = { bias, bias, bias, bias };
        acc = __builtin_amdgcn_mfma_f32_16x16x32_bf16(a0, b0, acc, 0, 0, 0);
        acc = __builtin_amdgcn_mfma_f32_16x16x32_bf16(a1, b1, acc, 0, 0, 0);
        const float w3 = s3w[m];
#pragma unroll
        for (int r = 0; r < 4; ++r) part[r] += fmaxf(acc[r], 0.f) * w3;
      }
#pragma unroll
      for (int r = 0; r < 4; ++r) {
        part[r] += __shfl_xor(part[r], 1);
        part[r] += __shfl_xor(part[r], 2);
        part[r] += __shfl_xor(part[r], 4);
        part[r] += __shfl_xor(part[r], 8);
      }
      if (rr == 0) {
        const int i0 = mt * 16 + kq * 4;
#pragma unroll
        for (int r = 0; r < 4; ++r) {
          int i = i0 + r;
          int a = i - (i / 20) * 20;
          out[base * 20 + i] = (a < nv) ? (part[r] + s3b0) : -1e8f;
        }
      }
    }
  }
}

extern "C" void kernel_launch(void* const* d_in, const int* in_sizes, int n_in,
                              void* d_out, int out_size, void* d_ws, size_t ws_size,
                              hipStream_t stream) {
  (void)in_sizes; (void)n_in; (void)out_size; (void)ws_size;
  float* out = (float*)d_out;
  float* ws = (float*)d_ws;

  hipLaunchKernelGGL(prep_kernel, dim3(33), dim3(256), 0, stream,
                     (const float*)d_in[6], (const int*)d_in[3], (const int*)d_in[4],
                     (const float*)d_in[19], (const float*)d_in[20],
                     (const float*)d_in[7], (const float*)d_in[21],
                     (const float*)d_in[9], (const float*)d_in[13],
                     (const float*)d_in[15], (const float*)d_in[17], ws);
  hipLaunchKernelGGL(policy_fused, dim3(32768 / TB), dim3(NT), 0, stream,
                     (const int*)d_in[0],  (const float*)d_in[1], (const int*)d_in[2],
                     (const int*)d_in[5],
                     (const float*)d_in[6],  (const float*)d_in[8],
                     (const float*)d_in[10], (const float*)d_in[11],
                     (const float*)d_in[12], (const float*)d_in[14],
                     (const float*)d_in[16], (const float*)d_in[18],
                     (const float*)d_in[22], (const float*)d_in[23],
                     (const float*)d_in[24], ws, out);
}

// Round 17
// 108.969 us; speedup vs baseline: 1.0051x; 1.0051x over previous
//
#include <hip/hip_runtime.h>
#include <hip/hip_bf16.h>

#define NT 512
#define TB 16   // batch elements per block

typedef unsigned short u16;
typedef unsigned int u32;
typedef __attribute__((ext_vector_type(8))) short short8v;  // 8 bf16 (4 VGPRs)
typedef __attribute__((ext_vector_type(4))) float f32x4;

__device__ __forceinline__ float bf2f(u16 u) {
  union { u32 i; float f; } v; v.i = ((u32)u) << 16; return v.f;
}
__device__ __forceinline__ float2 up2(u32 p) {
  union { u32 i; float f; } a, b;
  a.i = p << 16; b.i = p & 0xffff0000u;
  return make_float2(a.f, b.f);
}
__device__ __forceinline__ u16 f2bf(float f) {
  union { float f; u32 i; } v; v.f = f;
  u32 r = v.i + 0x7fffu + ((v.i >> 16) & 1u);  // round-to-nearest-even
  return (u16)(r >> 16);
}
// single-instruction pair pack: low16 = bf16(a), high16 = bf16(b)  [T12 recipe]
// NOTE (R15 post-mortem): only feed this values produced by ordinary VALU ops.
// Feeding MFMA accumulator registers DIRECTLY into this inline asm produced
// garbage (suspected missed MFMA->VALU hazard nops for inline-asm consumers).
__device__ __forceinline__ u32 pk2c(float a, float b) {
  u32 r;
  asm("v_cvt_pk_bf16_f32 %0, %1, %2" : "=v"(r) : "v"(a), "v"(b));
  return r;
}

// ws layout: f32 s1bp[20][64] @0 ; then u16 block at ws+1280:
//   wqkv [192][64] @0 | s2w [32][64] @12288 | ow [64][64] @14336 | g2w [32][64] @18432
//   c1w [128][96] @20480 | c2w [128][128] @32768 | s1wA [64][128] @49152
// Parallel prep (R13): blocks 0..31 convert weights; block 32 does arep+s1bp.
__global__ void prep_kernel(const float* __restrict__ emb, const int* __restrict__ act_idx,
                            const int* __restrict__ act_cnt, const float* __restrict__ s1w,
                            const float* __restrict__ s1b, const float* __restrict__ ipw,
                            const float* __restrict__ s2w, const float* __restrict__ ow,
                            const float* __restrict__ g2w, const float* __restrict__ c1w,
                            const float* __restrict__ c2w, float* __restrict__ ws) {
  __shared__ float s_arep[20][64];
  const int b = blockIdx.x, t = threadIdx.x;
  if (b < 32) {
    const int tid = b * 256 + t;             // 0..8191, stride 8192
    u16* wbf = (u16*)(ws + 1280);
    for (int o = tid; o < 12288; o += 8192) wbf[o] = f2bf(ipw[o]);
    for (int o = tid; o < 2048;  o += 8192) wbf[12288 + o] = f2bf(s2w[o]);
    for (int o = tid; o < 4096;  o += 8192) wbf[14336 + o] = f2bf(ow[o]);
    for (int o = tid; o < 2048;  o += 8192) wbf[18432 + o] = f2bf(g2w[o]);
    for (int o = tid; o < 12288; o += 8192) wbf[20480 + o] = f2bf(c1w[o]);
    for (int o = tid; o < 16384; o += 8192) wbf[32768 + o] = f2bf(c2w[o]);
    for (int o = tid; o < 8192;  o += 8192) {
      int f = o >> 7, k = o & 127;
      wbf[49152 + o] = f2bf(s1w[f * 192 + k]);
    }
  } else {
    for (int o = t; o < 20 * 64; o += 256) {
      int a = o >> 6, k = o & 63;
      int cnt = act_cnt[a];
      float sum = 0.f;
#pragma unroll
      for (int j = 0; j < 4; ++j)
        if (j < cnt) sum += emb[act_idx[a * 4 + j] * 64 + k];
      s_arep[a][k] = sum / (float)(cnt > 1 ? cnt : 1);
    }
    __syncthreads();
    for (int o = t; o < 20 * 64; o += 256) {
      int a = o >> 6, f = o & 63;
      const float* wr = s1w + f * 192 + 128;
      float acc = s1b[f];
#pragma unroll 8
      for (int k = 0; k < 64; ++k) acc += s_arep[a][k] * wr[k];
      ws[o] = acc;
    }
  }
}

// LDS map (bytes), total 52544; TB=16, NT=512 (8 waves):
//  [0..51200): x[128][72] u16 -> qkv[128][200] u16 (attention); ah overlays q-cols
//    then MLP bf16: hxbf[16][72]@0 g1bf[16][72]@2304 ctxin[16][104]@4608
//      ctxbf[16][136]@7936 ctx2bf[16][136]@12288 (end 16640)
//    then hbf[320][72] u16 @0..46080 (P9 staged; fused version regressed — R13)
//  s1a f32 [16][68] @46080..50432
//  extras: cards@51200 invlen@51712 gs@51776 (end 52544)
//  3 blocks/CU (LDS-bound), 24 waves/CU.
// R17 probe: P0a->P0b barrier removed (P0b reads its card from GLOBAL, not
// s_cards; P0a writes [51200,52544) / P0b writes [0,18432) — disjoint; all
// s_cards/s_gs/s_invlen consumers sit behind P1's internal full barrier).
__global__ __launch_bounds__(NT, 6) void policy_fused(
    const int* __restrict__ hand_cards, const float* __restrict__ game_state,
    const int* __restrict__ hand_size, const int* __restrict__ num_valid,
    const float* __restrict__ emb, const float* __restrict__ ipb,
    const float* __restrict__ ob, const float* __restrict__ g1w,
    const float* __restrict__ g1b, const float* __restrict__ g2b,
    const float* __restrict__ c1b, const float* __restrict__ c2b,
    const float* __restrict__ s2b, const float* __restrict__ s3w,
    const float* __restrict__ s3b, const float* __restrict__ ws,
    float* __restrict__ out)
{
  __shared__ __align__(16) unsigned char s_raw[52544];
  u16*   s_x     = (u16*)s_raw;                 // [128][72]
  u16*   s_qkv   = (u16*)s_raw;                 // [128][200]; ah -> cols 0..63
  u16*   s_hxbf  = (u16*)(s_raw + 0);           // [16][72]
  u16*   s_g1bf  = (u16*)(s_raw + 2304);        // [16][72]
  u16*   s_ctxin = (u16*)(s_raw + 4608);        // [16][104] hand|g
  u16*   s_ctxbf = (u16*)(s_raw + 7936);        // [16][136]
  u16*   s_ctx2bf= (u16*)(s_raw + 12288);       // [16][136]
  u16*   s_hbf   = (u16*)s_raw;                 // [320][72] (P9)
  float* s_s1a   = (float*)(s_raw + 46080);     // [16][68]
  int*   s_cards  = (int*)(s_raw + 51200);      // [128]
  float* s_invlen = (float*)(s_raw + 51712);    // [16]
  float* s_gs    = (float*)(s_raw + 51776);     // [16][12]

  const float* ws_s1bp = ws;                         // [20][64]
  const u16* wbf    = (const u16*)(ws + 1280);
  const u16* wqkv   = wbf;                           // [192][64]
  const u16* s2wbf  = wbf + 12288;                   // [32][64]
  const u16* owbf   = wbf + 14336;                   // [64][64]
  const u16* g2wbf  = wbf + 18432;                   // [32][64]
  const u16* c1wbf  = wbf + 20480;                   // [128][96]
  const u16* c2wbf  = wbf + 32768;                   // [128][128]
  const u16* s1wbf  = wbf + 49152;                   // [64][128]

  const int t = threadIdx.x;
  const int base = blockIdx.x * TB;
  const int lw = t & 63, wv = t >> 6;     // 8 waves
  const int kq = lw >> 4, rr = lw & 15;   // MFMA: A row / C col = rr; k-chunk & C row-group = kq
  const int row0 = kq * 4;

  // ---- P0a (no barrier after — see header comment) ----
  if (t < 128) s_cards[t] = hand_cards[base * 8 + t];
  if (t < TB) { int hs = hand_size[base + t]; s_invlen[t] = 1.0f / (float)(hs > 1 ? hs : 1); }
  if (t >= 128 && t < 128 + TB * 12) {
    int i = t - 128; s_gs[(i / 12) * 12 + (i % 12)] = game_state[(base + i / 12) * 12 + i % 12];
  }

  // ---- P0b: gather x = emb[cards] -> bf16 LDS (card direct from global) ----
  {
    int es = t >> 2, k0 = (t & 3) * 16;            // 128 tokens x 4 threads
    const float* src = emb + hand_cards[base * 8 + es] * 64 + k0;
    float4 v0 = *(const float4*)(src);
    float4 v1 = *(const float4*)(src + 4);
    float4 v2 = *(const float4*)(src + 8);
    float4 v3 = *(const float4*)(src + 12);
    uint4 pa = make_uint4(pk2c(v0.x,v0.y), pk2c(v0.z,v0.w), pk2c(v1.x,v1.y), pk2c(v1.z,v1.w));
    uint4 pb = make_uint4(pk2c(v2.x,v2.y), pk2c(v2.z,v2.w), pk2c(v3.x,v3.y), pk2c(v3.z,v3.w));
    *(uint4*)(s_x + es * 72 + k0) = pa;
    *(uint4*)(s_x + es * 72 + k0 + 8) = pb;
  }
  __syncthreads();

  // ---- P1: qkv = x @ ipw.T + ipb via MFMA (wave wv owns tokens 16wv..16wv+15) ----
  {
    const int tok = wv * 16 + rr;
    short8v a0 = *(const short8v*)(s_x + tok * 72 + kq * 8);
    short8v a1 = *(const short8v*)(s_x + tok * 72 + 32 + kq * 8);
    __syncthreads();   // A frags in regs; qkv may overwrite x
    const int trow = wv * 16 + row0;
    for (int n = 0; n < 12; ++n) {
      const int f = n * 16 + rr;
      short8v b0 = *(const short8v*)(wqkv + f * 64 + kq * 8);
      short8v b1 = *(const short8v*)(wqkv + f * 64 + 32 + kq * 8);
      float bias = ipb[f];
      f32x4 acc = { bias, bias, bias, bias };
      acc = __builtin_amdgcn_mfma_f32_16x16x32_bf16(a0, b0, acc, 0, 0, 0);
      acc = __builtin_amdgcn_mfma_f32_16x16x32_bf16(a1, b1, acc, 0, 0, 0);
#pragma unroll
      for (int r = 0; r < 4; ++r)
        s_qkv[(trow + r) * 200 + f] = f2bf(acc[r]);
    }
  }
  __syncthreads();

  // ---- P2+P4 merged: scores + softmax (in regs) + PV ; ah -> qkv q-cols ----
  {
    int e = t >> 5, h = (t >> 3) & 3, q = t & 7;   // e 0..15
    u16* qrow = s_qkv + (e * 8 + q) * 200 + h * 16;
    float qr[16];
    {
      uint4 ua = *(const uint4*)(qrow);
      uint4 ub = *(const uint4*)(qrow + 8);
      float2 f;
      f = up2(ua.x); qr[0]=f.x; qr[1]=f.y;  f = up2(ua.y); qr[2]=f.x; qr[3]=f.y;
      f = up2(ua.z); qr[4]=f.x; qr[5]=f.y;  f = up2(ua.w); qr[6]=f.x; qr[7]=f.y;
      f = up2(ub.x); qr[8]=f.x; qr[9]=f.y;  f = up2(ub.y); qr[10]=f.x; qr[11]=f.y;
      f = up2(ub.z); qr[12]=f.x; qr[13]=f.y; f = up2(ub.w); qr[14]=f.x; qr[15]=f.y;
    }
    float sc[8];
#pragma unroll
    for (int kk = 0; kk < 8; ++kk) {
      const u16* krow = s_qkv + (e * 8 + kk) * 200 + 64 + h * 16;
      uint4 ua = *(const uint4*)(krow);
      uint4 ub = *(const uint4*)(krow + 8);
      float a0 = 0.f;
      float2 f;
      f = up2(ua.x); a0 += qr[0]*f.x + qr[1]*f.y;
      f = up2(ua.y); a0 += qr[2]*f.x + qr[3]*f.y;
      f = up2(ua.z); a0 += qr[4]*f.x + qr[5]*f.y;
      f = up2(ua.w); a0 += qr[6]*f.x + qr[7]*f.y;
      f = up2(ub.x); a0 += qr[8]*f.x + qr[9]*f.y;
      f = up2(ub.y); a0 += qr[10]*f.x + qr[11]*f.y;
      f = up2(ub.z); a0 += qr[12]*f.x + qr[13]*f.y;
      f = up2(ub.w); a0 += qr[14]*f.x + qr[15]*f.y;
      sc[kk] = (s_cards[e * 8 + kk] != 0) ? a0 * 0.25f : -1e9f;
    }
    float m = sc[0];
#pragma unroll
    for (int kk = 1; kk < 8; ++kk) m = fmaxf(m, sc[kk]);
    float ssum = 0.f;
#pragma unroll
    for (int kk = 0; kk < 8; ++kk) { sc[kk] = __expf(sc[kk] - m); ssum += sc[kk]; }
    float inv = 1.f / ssum;
#pragma unroll
    for (int kk = 0; kk < 8; ++kk) sc[kk] *= inv;
    float acc[16];
#pragma unroll
    for (int d = 0; d < 16; ++d) acc[d] = 0.f;
#pragma unroll
    for (int kk = 0; kk < 8; ++kk) {
      const u16* vrow = s_qkv + (e * 8 + kk) * 200 + 128 + h * 16;
      uint4 ua = *(const uint4*)(vrow);
      uint4 ub = *(const uint4*)(vrow + 8);
      float2 f;
      f = up2(ua.x); acc[0] += sc[kk]*f.x; acc[1] += sc[kk]*f.y;
      f = up2(ua.y); acc[2] += sc[kk]*f.x; acc[3] += sc[kk]*f.y;
      f = up2(ua.z); acc[4] += sc[kk]*f.x; acc[5] += sc[kk]*f.y;
      f = up2(ua.w); acc[6] += sc[kk]*f.x; acc[7] += sc[kk]*f.y;
      f = up2(ub.x); acc[8] += sc[kk]*f.x; acc[9] += sc[kk]*f.y;
      f = up2(ub.y); acc[10] += sc[kk]*f.x; acc[11] += sc[kk]*f.y;
      f = up2(ub.z); acc[12] += sc[kk]*f.x; acc[13] += sc[kk]*f.y;
      f = up2(ub.w); acc[14] += sc[kk]*f.x; acc[15] += sc[kk]*f.y;
    }
    uint4 oa = make_uint4(pk2c(acc[0],acc[1]), pk2c(acc[2],acc[3]), pk2c(acc[4],acc[5]), pk2c(acc[6],acc[7]));
    uint4 oc = make_uint4(pk2c(acc[8],acc[9]), pk2c(acc[10],acc[11]), pk2c(acc[12],acc[13]), pk2c(acc[14],acc[15]));
    *(uint4*)(qrow) = oa;
    *(uint4*)(qrow + 8) = oc;
  }
  __syncthreads();

  // ---- P5a: stage hx (sum_q ah) + g1 into regs; barrier; write over dead region ----
  {
    int e = t >> 5, k2 = (t & 31) * 2;             // hx: (e 0..15, col pair)
    float s0 = 0.f, s1 = 0.f;
#pragma unroll
    for (int q = 0; q < 8; ++q) {
      float2 f = up2(*(const u32*)(s_qkv + (e * 8 + q) * 200 + k2));
      s0 += f.x; s1 += f.y;
    }
    int e1 = t >> 6, f1 = t & 63;                  // g1: e1 0..7
    float ga = g1b[f1];
#pragma unroll
    for (int k = 0; k < 12; ++k) ga += s_gs[e1 * 12 + k] * g1w[f1 * 12 + k];
    int e2 = e1 + 8;
    float gb = g1b[f1];
#pragma unroll
    for (int k = 0; k < 12; ++k) gb += s_gs[e2 * 12 + k] * g1w[f1 * 12 + k];
    __syncthreads();   // all ah reads done; attention region now dead
    *(u32*)(s_hxbf + e * 72 + k2) = pk2c(s0, s1);
    s_g1bf[e1 * 72 + f1] = f2bf(fmaxf(ga, 0.f));
    s_g1bf[e2 * 72 + f1] = f2bf(fmaxf(gb, 0.f));
  }
  __syncthreads();

  // ---- P5b: hand (waves 0..3) -> ctxin[:, :64] ; g2 (waves 4..5) -> ctxin[:, 64:96] ----
  {
    if (wv < 4) {
      short8v a0 = *(const short8v*)(s_hxbf + rr * 72 + kq * 8);
      short8v a1 = *(const short8v*)(s_hxbf + rr * 72 + 32 + kq * 8);
      const int f = wv * 16 + rr;
      short8v b0 = *(const short8v*)(owbf + f * 64 + kq * 8);
      short8v b1 = *(const short8v*)(owbf + f * 64 + 32 + kq * 8);
      float bias = 8.f * ob[f];
      f32x4 acc = { bias, bias, bias, bias };
      acc = __builtin_amdgcn_mfma_f32_16x16x32_bf16(a0, b0, acc, 0, 0, 0);
      acc = __builtin_amdgcn_mfma_f32_16x16x32_bf16(a1, b1, acc, 0, 0, 0);
#pragma unroll
      for (int r = 0; r < 4; ++r) {
        int row = row0 + r;
        s_ctxin[row * 104 + f] = f2bf(acc[r] * s_invlen[row]);
      }
    } else if (wv < 6) {
      short8v g0 = *(const short8v*)(s_g1bf + rr * 72 + kq * 8);
      short8v g1v = *(const short8v*)(s_g1bf + rr * 72 + 32 + kq * 8);
      const int f2 = (wv - 4) * 16 + rr;
      short8v c0 = *(const short8v*)(g2wbf + f2 * 64 + kq * 8);
      short8v c1 = *(const short8v*)(g2wbf + f2 * 64 + 32 + kq * 8);
      float b2 = g2b[f2];
      f32x4 acc2 = { b2, b2, b2, b2 };
      acc2 = __builtin_amdgcn_mfma_f32_16x16x32_bf16(g0, c0, acc2, 0, 0, 0);
      acc2 = __builtin_amdgcn_mfma_f32_16x16x32_bf16(g1v, c1, acc2, 0, 0, 0);
#pragma unroll
      for (int r = 0; r < 4; ++r) {
        int row = row0 + r;
        s_ctxin[row * 104 + 64 + f2] = f2bf(fmaxf(acc2[r], 0.f));
      }
    }
  }
  __syncthreads();

  // ---- P6: ctx = relu(ctxin @ c1.T + c1b), K=96 N=128 (8 waves x 16 outputs) ----
  {
    short8v a0 = *(const short8v*)(s_ctxin + rr * 104 + kq * 8);
    short8v a1 = *(const short8v*)(s_ctxin + rr * 104 + 32 + kq * 8);
    short8v a2 = *(const short8v*)(s_ctxin + rr * 104 + 64 + kq * 8);
    const int f = wv * 16 + rr;
    short8v b0 = *(const short8v*)(c1wbf + f * 96 + kq * 8);
    short8v b1 = *(const short8v*)(c1wbf + f * 96 + 32 + kq * 8);
    short8v b2 = *(const short8v*)(c1wbf + f * 96 + 64 + kq * 8);
    float bias = c1b[f];
    f32x4 acc = { bias, bias, bias, bias };
    acc = __builtin_amdgcn_mfma_f32_16x16x32_bf16(a0, b0, acc, 0, 0, 0);
    acc = __builtin_amdgcn_mfma_f32_16x16x32_bf16(a1, b1, acc, 0, 0, 0);
    acc = __builtin_amdgcn_mfma_f32_16x16x32_bf16(a2, b2, acc, 0, 0, 0);
#pragma unroll
    for (int r = 0; r < 4; ++r) {
      int row = row0 + r;
      s_ctxbf[row * 136 + f] = f2bf(fmaxf(acc[r], 0.f));
    }
  }
  __syncthreads();

  // ---- P7: ctx2 = relu(ctx @ c2.T + c2b), K=128 N=128 ----
  {
    short8v a0 = *(const short8v*)(s_ctxbf + rr * 136 + kq * 8);
    short8v a1 = *(const short8v*)(s_ctxbf + rr * 136 + 32 + kq * 8);
    short8v a2 = *(const short8v*)(s_ctxbf + rr * 136 + 64 + kq * 8);
    short8v a3 = *(const short8v*)(s_ctxbf + rr * 136 + 96 + kq * 8);
    const int f = wv * 16 + rr;
    short8v b0 = *(const short8v*)(c2wbf + f * 128 + kq * 8);
    short8v b1 = *(const short8v*)(c2wbf + f * 128 + 32 + kq * 8);
    short8v b2 = *(const short8v*)(c2wbf + f * 128 + 64 + kq * 8);
    short8v b3 = *(const short8v*)(c2wbf + f * 128 + 96 + kq * 8);
    float bias = c2b[f];
    f32x4 acc = { bias, bias, bias, bias };
    acc = __builtin_amdgcn_mfma_f32_16x16x32_bf16(a0, b0, acc, 0, 0, 0);
    acc = __builtin_amdgcn_mfma_f32_16x16x32_bf16(a1, b1, acc, 0, 0, 0);
    acc = __builtin_amdgcn_mfma_f32_16x16x32_bf16(a2, b2, acc, 0, 0, 0);
    acc = __builtin_amdgcn_mfma_f32_16x16x32_bf16(a3, b3, acc, 0, 0, 0);
#pragma unroll
    for (int r = 0; r < 4; ++r) {
      int row = row0 + r;
      s_ctx2bf[row * 136 + f] = f2bf(fmaxf(acc[r], 0.f));
    }
  }
  __syncthreads();

  // ---- P8: s1a = ctx2 @ s1w[:,:128].T (f32 out), K=128 N=64 (waves 0..3) ----
  if (wv < 4) {
    short8v a0 = *(const short8v*)(s_ctx2bf + rr * 136 + kq * 8);
    short8v a1 = *(const short8v*)(s_ctx2bf + rr * 136 + 32 + kq * 8);
    short8v a2 = *(const short8v*)(s_ctx2bf + rr * 136 + 64 + kq * 8);
    short8v a3 = *(const short8v*)(s_ctx2bf + rr * 136 + 96 + kq * 8);
    const int f = wv * 16 + rr;
    short8v b0 = *(const short8v*)(s1wbf + f * 128 + kq * 8);
    short8v b1 = *(const short8v*)(s1wbf + f * 128 + 32 + kq * 8);
    short8v b2 = *(const short8v*)(s1wbf + f * 128 + 64 + kq * 8);
    short8v b3 = *(const short8v*)(s1wbf + f * 128 + 96 + kq * 8);
    f32x4 acc = { 0.f, 0.f, 0.f, 0.f };
    acc = __builtin_amdgcn_mfma_f32_16x16x32_bf16(a0, b0, acc, 0, 0, 0);
    acc = __builtin_amdgcn_mfma_f32_16x16x32_bf16(a1, b1, acc, 0, 0, 0);
    acc = __builtin_amdgcn_mfma_f32_16x16x32_bf16(a2, b2, acc, 0, 0, 0);
    acc = __builtin_amdgcn_mfma_f32_16x16x32_bf16(a3, b3, acc, 0, 0, 0);
#pragma unroll
    for (int r = 0; r < 4; ++r)
      s_s1a[(row0 + r) * 68 + f] = acc[r];
  }
  __syncthreads();

  // ---- P9a: h[i=e*20+a][j] = relu(s1a[e][j] + s1bp[a][j]) -> bf16 [320][72] ----
  for (int o = t; o < 320 * 32; o += NT) {
    int i = o >> 5, j = (o & 31) * 2;
    int e = i / 20, a = i - e * 20;
    float2 sv = *(const float2*)(s_s1a + e * 68 + j);
    float2 bv = *(const float2*)(ws_s1bp + a * 64 + j);
    float v0 = fmaxf(sv.x + bv.x, 0.f), v1 = fmaxf(sv.y + bv.y, 0.f);
    *(u32*)(s_hbf + i * 72 + j) = pk2c(v0, v1);
  }
  __syncthreads();

  // ---- P9b: score = relu(h @ s2w.T + s2b) . s3w + s3b via MFMA (20 M-tiles / 8 waves) ----
  {
    const int nv = num_valid[0];
    const float s3b0 = s3b[0];
    for (int mt = wv; mt < 20; mt += 8) {
      const int row = mt * 16 + rr;
      short8v a0 = *(const short8v*)(s_hbf + row * 72 + kq * 8);
      short8v a1 = *(const short8v*)(s_hbf + row * 72 + 32 + kq * 8);
      float part[4] = {0.f, 0.f, 0.f, 0.f};
#pragma unroll
      for (int ntile = 0; ntile < 2; ++ntile) {
        const int m = ntile * 16 + rr;
        short8v b0 = *(const short8v*)(s2wbf + m * 64 + kq * 8);
        short8v b1 = *(const short8v*)(s2wbf + m * 64 + 32 + kq * 8);
        float bias = s2b[m];
        f32x4 acc = { bias, bias, bias, bias };
        acc = __builtin_amdgcn_mfma_f32_16x16x32_bf16(a0, b0, acc, 0, 0, 0);
        acc = __builtin_amdgcn_mfma_f32_16x16x32_bf16(a1, b1, acc, 0, 0, 0);
        const float w3 = s3w[m];
#pragma unroll
        for (int r = 0; r < 4; ++r) part[r] += fmaxf(acc[r], 0.f) * w3;
      }
#pragma unroll
      for (int r = 0; r < 4; ++r) {
        part[r] += __shfl_xor(part[r], 1);
        part[r] += __shfl_xor(part[r], 2);
        part[r] += __shfl_xor(part[r], 4);
        part[r] += __shfl_xor(part[r], 8);
      }
      if (rr == 0) {
        const int i0 = mt * 16 + kq * 4;
#pragma unroll
        for (int r = 0; r < 4; ++r) {
          int i = i0 + r;
          int a = i - (i / 20) * 20;
          out[base * 20 + i] = (a < nv) ? (part[r] + s3b0) : -1e8f;
        }
      }
    }
  }
}

extern "C" void kernel_launch(void* const* d_in, const int* in_sizes, int n_in,
                              void* d_out, int out_size, void* d_ws, size_t ws_size,
                              hipStream_t stream) {
  (void)in_sizes; (void)n_in; (void)out_size; (void)ws_size;
  float* out = (float*)d_out;
  float* ws = (float*)d_ws;

  hipLaunchKernelGGL(prep_kernel, dim3(33), dim3(256), 0, stream,
                     (const float*)d_in[6], (const int*)d_in[3], (const int*)d_in[4],
                     (const float*)d_in[19], (const float*)d_in[20],
                     (const float*)d_in[7], (const float*)d_in[21],
                     (const float*)d_in[9], (const float*)d_in[13],
                     (const float*)d_in[15], (const float*)d_in[17], ws);
  hipLaunchKernelGGL(policy_fused, dim3(32768 / TB), dim3(NT), 0, stream,
                     (const int*)d_in[0],  (const float*)d_in[1], (const int*)d_in[2],
                     (const int*)d_in[5],
                     (const float*)d_in[6],  (const float*)d_in[8],
                     (const float*)d_in[10], (const float*)d_in[11],
                     (const float*)d_in[12], (const float*)d_in[14],
                     (const float*)d_in[16], (const float*)d_in[18],
                     (const float*)d_in[22], (const float*)d_in[23],
                     (const float*)d_in[24], ws, out);
}